// Round 1
// baseline (195.771 us; speedup 1.0000x reference)
//
#include <hip/hip_runtime.h>

// ---------------------------------------------------------------------------
// KAN-conv MLP, fp32 throughout.
// Cardinal cubic B-spline: basis_i(x) = B3(u - i), u = 2.5x + 5.5.
// Only 4 taps nonzero; spline weights zero-padded to 16 slots (idx = t..t+3).
// ---------------------------------------------------------------------------

struct Feat { float s, w0, w1, w2, w3; int t; };

__device__ __forceinline__ Feat kan_feat(float v) {
  Feat r;
  r.s = v / (1.0f + __expf(-v));               // silu
  float u  = fmaf(v, 2.5f, 5.5f);
  float tf = floorf(u);
  float f  = u - tf;
  float f2 = f * f, f3 = f2 * f;
  float om = 1.0f - f;
  const float c6 = 1.0f / 6.0f;
  r.w0 = om * om * om * c6;                        // basis i = t-3
  r.w1 = (3.0f * f3 - 6.0f * f2 + 4.0f) * c6;      // i = t-2
  r.w2 = (-3.0f * f3 + 3.0f * f2 + 3.0f * f + 1.0f) * c6; // i = t-1
  r.w3 = f3 * c6;                                  // i = t
  if (!(u >= 0.0f && u < 11.0f)) { r.w0 = r.w1 = r.w2 = r.w3 = 0.0f; }
  int ti = (int)tf;
  r.t = ti < 0 ? 0 : (ti > 10 ? 10 : ti);
  return r;
}

// --------------------------- conv1 (1->5) + maxpool ------------------------
// x: [2048,1,28,28] -> h1: [2048,5,13,13]
__global__ __launch_bounds__(256) void k_conv1_pool(
    const float* __restrict__ x, const float* __restrict__ bw1,
    const float* __restrict__ sw1, float* __restrict__ h1) {
  __shared__ float sbw[45];        // [o*9+p]
  __shared__ float ssw[9 * 5 * 16]; // [(p*5+o)*16 + i16], i16 = basis_i + 3
  for (int l = threadIdx.x; l < 45; l += 256) sbw[l] = bw1[l];
  for (int l = threadIdx.x; l < 720; l += 256) {
    int p = l / 80, rest = l % 80, o = rest / 16, i16 = rest % 16;
    int i = i16 - 3;
    ssw[l] = (i >= 0 && i < 8) ? sw1[(o * 9 + p) * 8 + i] : 0.0f;
  }
  __syncthreads();
  int idx = blockIdx.x * 256 + threadIdx.x;
  if (idx >= 2048 * 169) return;
  int b = idx / 169, r = idx % 169, py = r / 13, px = r % 13;
  const float* xb = x + b * 784;
  float best[5] = {-1e30f, -1e30f, -1e30f, -1e30f, -1e30f};
  #pragma unroll
  for (int dy = 0; dy < 2; ++dy) {
    #pragma unroll
    for (int dx = 0; dx < 2; ++dx) {
      int y = py * 2 + dy, xx = px * 2 + dx;
      float a[5] = {0.f, 0.f, 0.f, 0.f, 0.f};
      #pragma unroll
      for (int p = 0; p < 9; ++p) {
        int ky = p / 3, kx = p % 3;
        float v = xb[(y + ky) * 28 + (xx + kx)];
        Feat ft = kan_feat(v);
        const float* sp = &ssw[(p * 5) * 16 + ft.t];
        #pragma unroll
        for (int o = 0; o < 5; ++o) {
          float sv = fmaf(ft.w0, sp[o * 16 + 0],
                     fmaf(ft.w1, sp[o * 16 + 1],
                     fmaf(ft.w2, sp[o * 16 + 2], ft.w3 * sp[o * 16 + 3])));
          a[o] += fmaf(ft.s, sbw[o * 9 + p], sv);
        }
      }
      #pragma unroll
      for (int o = 0; o < 5; ++o) best[o] = fmaxf(best[o], a[o]);
    }
  }
  #pragma unroll
  for (int o = 0; o < 5; ++o)
    h1[((b * 5 + o) * 13 + py) * 13 + px] = best[o];
}

// --------------------------- generic KAN conv ------------------------------
// hin: [2048,CIN,HIN,HIN] -> hout: [2048,COUT,HIN-2,HIN-2]
// patch index is channel-major: in = c*9 + ky*3 + kx
template <int CIN, int HIN, int COUT>
__global__ __launch_bounds__(256) void k_kanconv(
    const float* __restrict__ hin, const float* __restrict__ bw,
    const float* __restrict__ sw, float* __restrict__ hout) {
  constexpr int HOUT = HIN - 2;
  constexpr int NIN = CIN * 9;
  __shared__ float sbw[COUT * NIN];        // [o*NIN+in]
  __shared__ float ssw[NIN * COUT * 16];   // [(in*COUT+o)*16 + i16]
  for (int l = threadIdx.x; l < COUT * NIN; l += 256) sbw[l] = bw[l];
  for (int l = threadIdx.x; l < NIN * COUT * 16; l += 256) {
    int in = l / (COUT * 16), rest = l % (COUT * 16), o = rest / 16, i16 = rest % 16;
    int i = i16 - 3;
    ssw[l] = (i >= 0 && i < 8) ? sw[(o * NIN + in) * 8 + i] : 0.0f;
  }
  __syncthreads();
  int idx = blockIdx.x * 256 + threadIdx.x;
  if (idx >= 2048 * HOUT * HOUT) return;
  int b = idx / (HOUT * HOUT), r = idx % (HOUT * HOUT), y = r / HOUT, xx = r % HOUT;
  float a[COUT];
  #pragma unroll
  for (int o = 0; o < COUT; ++o) a[o] = 0.0f;
  for (int c = 0; c < CIN; ++c) {
    const float* pb = hin + ((b * CIN + c) * HIN + y) * HIN + xx;
    #pragma unroll
    for (int p = 0; p < 9; ++p) {
      int ky = p / 3, kx = p % 3;
      float v = pb[ky * HIN + kx];
      Feat ft = kan_feat(v);
      int in = c * 9 + p;
      const float* sp = &ssw[(in * COUT) * 16 + ft.t];
      #pragma unroll
      for (int o = 0; o < COUT; ++o) {
        float sv = fmaf(ft.w0, sp[o * 16 + 0],
                   fmaf(ft.w1, sp[o * 16 + 1],
                   fmaf(ft.w2, sp[o * 16 + 2], ft.w3 * sp[o * 16 + 3])));
        a[o] += fmaf(ft.s, sbw[o * NIN + in], sv);
      }
    }
  }
  #pragma unroll
  for (int o = 0; o < COUT; ++o)
    hout[((b * COUT + o) * HOUT + y) * HOUT + xx] = a[o];
}

// --------------------------- FC1: [2048,162]x[500,162]^T + b, ReLU ----------
__global__ __launch_bounds__(256) void k_fc1(
    const float* __restrict__ A, const float* __restrict__ W,
    const float* __restrict__ bias, float* __restrict__ out) {
  __shared__ float As[16][64];
  __shared__ float Ws[16][64];
  int bm = (blockIdx.x % 32) * 64;   // 2048/64 tiles
  int bn = (blockIdx.x / 32) * 64;   // 8 n-tiles (512 >= 500)
  int tid = threadIdx.x;
  int tx = tid % 16, ty = tid / 16;
  float acc[4][4];
  #pragma unroll
  for (int i = 0; i < 4; ++i)
    #pragma unroll
    for (int j = 0; j < 4; ++j) acc[i][j] = 0.0f;
  for (int k0 = 0; k0 < 162; k0 += 16) {
    #pragma unroll
    for (int e = 0; e < 4; ++e) {
      int l = tid + e * 256;               // 0..1023
      int m = l / 16, k = l % 16;
      int gk = k0 + k;
      As[k][m] = (gk < 162) ? A[(bm + m) * 162 + gk] : 0.0f;
      int gn = bn + m;
      Ws[k][m] = (gk < 162 && gn < 500) ? W[gn * 162 + gk] : 0.0f;
    }
    __syncthreads();
    #pragma unroll
    for (int k = 0; k < 16; ++k) {
      float4 av = *(const float4*)&As[k][ty * 4];
      float4 wv = *(const float4*)&Ws[k][tx * 4];
      float a4[4] = {av.x, av.y, av.z, av.w};
      float w4[4] = {wv.x, wv.y, wv.z, wv.w};
      #pragma unroll
      for (int i = 0; i < 4; ++i)
        #pragma unroll
        for (int j = 0; j < 4; ++j)
          acc[i][j] = fmaf(a4[i], w4[j], acc[i][j]);
    }
    __syncthreads();
  }
  #pragma unroll
  for (int i = 0; i < 4; ++i) {
    int m = bm + ty * 4 + i;
    #pragma unroll
    for (int j = 0; j < 4; ++j) {
      int n = bn + tx * 4 + j;
      if (n < 500) {
        float v = acc[i][j] + bias[n];
        out[m * 500 + n] = v > 0.0f ? v : 0.0f;
      }
    }
  }
}

// --------------------------- FC2: [2048,500]x[10,500]^T + b -----------------
__global__ __launch_bounds__(256) void k_fc2(
    const float* __restrict__ H, const float* __restrict__ W2,
    const float* __restrict__ b2, float* __restrict__ out) {
  int gtid = blockIdx.x * 256 + threadIdx.x;
  int b = gtid / 64, lane = gtid % 64;
  if (b >= 2048) return;
  float acc[10];
  #pragma unroll
  for (int o = 0; o < 10; ++o) acc[o] = 0.0f;
  for (int k = lane; k < 500; k += 64) {
    float a = H[b * 500 + k];
    #pragma unroll
    for (int o = 0; o < 10; ++o) acc[o] = fmaf(a, W2[o * 500 + k], acc[o]);
  }
  #pragma unroll
  for (int off = 32; off > 0; off >>= 1) {
    #pragma unroll
    for (int o = 0; o < 10; ++o) acc[o] += __shfl_down(acc[o], off);
  }
  if (lane == 0) {
    #pragma unroll
    for (int o = 0; o < 10; ++o) out[b * 10 + o] = acc[o] + b2[o];
  }
}

// ---------------------------------------------------------------------------
extern "C" void kernel_launch(void* const* d_in, const int* in_sizes, int n_in,
                              void* d_out, int out_size, void* d_ws, size_t ws_size,
                              hipStream_t stream) {
  (void)in_sizes; (void)n_in; (void)out_size; (void)ws_size;
  const float* x   = (const float*)d_in[0];
  const float* bw1 = (const float*)d_in[1];
  const float* sw1 = (const float*)d_in[2];
  const float* bw2 = (const float*)d_in[3];
  const float* sw2 = (const float*)d_in[4];
  const float* bw3 = (const float*)d_in[5];
  const float* sw3 = (const float*)d_in[6];
  const float* w1  = (const float*)d_in[7];
  const float* b1  = (const float*)d_in[8];
  const float* w2  = (const float*)d_in[9];
  const float* b2  = (const float*)d_in[10];
  float* out = (float*)d_out;

  char* ws = (char*)d_ws;
  float* h1  = (float*)(ws);                 // [2048,5,13,13]  6,922,240 B
  float* h2  = (float*)(ws + 6922240);       // [2048,5,11,11]  4,956,160 B
  float* h3  = (float*)(ws + 11878400);      // [2048,162]      1,327,104 B
  float* fc1 = (float*)(ws + 13205504);      // [2048,500]      4,096,000 B

  k_conv1_pool<<<1352, 256, 0, stream>>>(x, bw1, sw1, h1);           // 2048*169/256
  k_kanconv<5, 13, 5><<<968, 256, 0, stream>>>(h1, bw2, sw2, h2);    // 2048*121/256
  k_kanconv<5, 11, 2><<<648, 256, 0, stream>>>(h2, bw3, sw3, h3);    // 2048*81/256
  k_fc1<<<256, 256, 0, stream>>>(h3, w1, b1, fc1);
  k_fc2<<<512, 256, 0, stream>>>(fc1, w2, b2, out);
}

// Round 2
// 193.755 us; speedup vs baseline: 1.0104x; 1.0104x over previous
//
#include <hip/hip_runtime.h>

// ---------------------------------------------------------------------------
// KAN-conv MLP, fp32.
// Cardinal cubic B-spline: basis_i(x) = B3(u - i), u = 2.5x + 5.5 (4 taps).
// Per image: featurize pixels ONCE into LDS as dense phi[pix][9] =
// [B0..B7, silu]; conv = dense contraction with merged weights W[in][j][o]
// (wave-uniform -> scalar loads), built by k_prep into d_ws.
// ---------------------------------------------------------------------------

__device__ __forceinline__ void featurize(float v, float* __restrict__ dst) {
  float s = v / (1.0f + __expf(-v));
  float u  = fmaf(v, 2.5f, 5.5f);
  float tf = floorf(u);
  float f  = u - tf;
  float f2 = f * f, f3 = f2 * f;
  float om = 1.0f - f;
  const float c6 = 1.0f / 6.0f;
  float w0 = om * om * om * c6;
  float w1 = (3.0f * f3 - 6.0f * f2 + 4.0f) * c6;
  float w2 = (-3.0f * f3 + 3.0f * f2 + 3.0f * f + 1.0f) * c6;
  float w3 = f3 * c6;
  int t = (int)tf;
  bool in = (u >= 0.0f && u < 11.0f);
  #pragma unroll
  for (int j = 0; j < 8; ++j) dst[j] = 0.0f;
  if (in) {                       // t in [0,10]; basis index i = t-3+k, keep 0..7
    if (t >= 3)            dst[t - 3] = w0;
    if (t >= 2 && t <= 9)  dst[t - 2] = w1;
    if (t >= 1 && t <= 8)  dst[t - 1] = w2;
    if (t <= 7)            dst[t]     = w3;
  }
  dst[8] = s;
}

// ------------------ weight prep: W[in][j][o], j=8 -> base weight ------------
__global__ __launch_bounds__(256) void k_prep(
    const float* __restrict__ bw1, const float* __restrict__ sw1,
    const float* __restrict__ bw2, const float* __restrict__ sw2,
    const float* __restrict__ bw3, const float* __restrict__ sw3,
    float* __restrict__ W1d, float* __restrict__ W2d, float* __restrict__ W3d) {
  int t = blockIdx.x * 256 + threadIdx.x;
  if (t < 405) {   // layer1: NIN=9, COUT=5
    int o = t % 5, r = t / 5, j = r % 9, in = r / 9;
    W1d[t] = (j < 8) ? sw1[(o * 9 + in) * 8 + j] : bw1[o * 9 + in];
  }
  if (t < 2025) {  // layer2: NIN=45, COUT=5
    int o = t % 5, r = t / 5, j = r % 9, in = r / 9;
    W2d[t] = (j < 8) ? sw2[(o * 45 + in) * 8 + j] : bw2[o * 45 + in];
  }
  if (t < 810) {   // layer3: NIN=45, COUT=2
    int o = t % 2, r = t / 2, j = r % 9, in = r / 9;
    W3d[t] = (j < 8) ? sw3[(o * 45 + in) * 8 + j] : bw3[o * 45 + in];
  }
}

// ------------------ conv1 (1->5) + 2x2 maxpool, one image per block ---------
__global__ __launch_bounds__(256) void k_conv1_pool(
    const float* __restrict__ x, const float* __restrict__ W1d,
    float* __restrict__ h1) {
  __shared__ float phi[784 * 9];           // 28,224 B
  int b = blockIdx.x;
  for (int l = threadIdx.x; l < 784; l += 256)
    featurize(x[b * 784 + l], &phi[l * 9]);
  __syncthreads();
  int w = threadIdx.x;
  if (w >= 169) return;
  int py = w / 13, px = w % 13;
  float best[5] = {-1e30f, -1e30f, -1e30f, -1e30f, -1e30f};
  #pragma unroll
  for (int dy = 0; dy < 2; ++dy) {
    #pragma unroll
    for (int dx = 0; dx < 2; ++dx) {
      int y = py * 2 + dy, xx = px * 2 + dx;
      float acc[5] = {0.f, 0.f, 0.f, 0.f, 0.f};
      #pragma unroll 1
      for (int ky = 0; ky < 3; ++ky) {
        const float* rp = &phi[((y + ky) * 28 + xx) * 9];
        const float* wp = W1d + ky * 135;  // (ky*3+kx)*9+j -> ky*27 + q, *5
        float ph[27];
        #pragma unroll
        for (int q = 0; q < 27; ++q) ph[q] = rp[q];
        #pragma unroll
        for (int q = 0; q < 27; ++q)
          #pragma unroll
          for (int o = 0; o < 5; ++o)
            acc[o] = fmaf(ph[q], wp[q * 5 + o], acc[o]);
      }
      #pragma unroll
      for (int o = 0; o < 5; ++o) best[o] = fmaxf(best[o], acc[o]);
    }
  }
  #pragma unroll
  for (int o = 0; o < 5; ++o)
    h1[((b * 5 + o) * 13 + py) * 13 + px] = best[o];
}

// ------------------ generic KAN conv, G images per block --------------------
template <int CIN, int HIN, int COUT, int G>
__global__ __launch_bounds__(256) void k_kanconv(
    const float* __restrict__ hin, const float* __restrict__ Wd,
    float* __restrict__ hout, int nimg) {
  constexpr int HOUT = HIN - 2;
  constexpr int NPIX = CIN * HIN * HIN;
  __shared__ float phi[G * NPIX * 9];
  int b0 = blockIdx.x * G;
  for (int l = threadIdx.x; l < G * NPIX; l += 256) {
    int img = l / NPIX, pix = l - img * NPIX;
    if (b0 + img < nimg)
      featurize(hin[(b0 + img) * NPIX + pix], &phi[l * 9]);
  }
  __syncthreads();
  int w = threadIdx.x;
  if (w >= G * HOUT * HOUT) return;
  int img = w / (HOUT * HOUT), pos = w - img * (HOUT * HOUT);
  int y = pos / HOUT, x = pos - y * HOUT;
  int b = b0 + img;
  if (b >= nimg) return;
  float acc[COUT];
  #pragma unroll
  for (int o = 0; o < COUT; ++o) acc[o] = 0.0f;
  #pragma unroll 1
  for (int c = 0; c < CIN; ++c) {
    #pragma unroll 1
    for (int ky = 0; ky < 3; ++ky) {
      const float* rp = &phi[(((img * CIN + c) * HIN + (y + ky)) * HIN + x) * 9];
      const float* wp = Wd + (c * 9 + ky * 3) * 9 * COUT;
      float ph[27];
      #pragma unroll
      for (int q = 0; q < 27; ++q) ph[q] = rp[q];
      #pragma unroll
      for (int q = 0; q < 27; ++q)
        #pragma unroll
        for (int o = 0; o < COUT; ++o)
          acc[o] = fmaf(ph[q], wp[q * COUT + o], acc[o]);
    }
  }
  #pragma unroll
  for (int o = 0; o < COUT; ++o)
    hout[((b * COUT + o) * HOUT + y) * HOUT + x] = acc[o];
}

// --------------------------- FC1: [2048,162]x[500,162]^T + b, ReLU ----------
__global__ __launch_bounds__(256) void k_fc1(
    const float* __restrict__ A, const float* __restrict__ W,
    const float* __restrict__ bias, float* __restrict__ out) {
  __shared__ float As[16][64];
  __shared__ float Ws[16][64];
  int bm = (blockIdx.x % 32) * 64;
  int bn = (blockIdx.x / 32) * 64;
  int tid = threadIdx.x;
  int tx = tid % 16, ty = tid / 16;
  float acc[4][4];
  #pragma unroll
  for (int i = 0; i < 4; ++i)
    #pragma unroll
    for (int j = 0; j < 4; ++j) acc[i][j] = 0.0f;
  for (int k0 = 0; k0 < 162; k0 += 16) {
    #pragma unroll
    for (int e = 0; e < 4; ++e) {
      int l = tid + e * 256;
      int m = l / 16, k = l % 16;
      int gk = k0 + k;
      As[k][m] = (gk < 162) ? A[(bm + m) * 162 + gk] : 0.0f;
      int gn = bn + m;
      Ws[k][m] = (gk < 162 && gn < 500) ? W[gn * 162 + gk] : 0.0f;
    }
    __syncthreads();
    #pragma unroll
    for (int k = 0; k < 16; ++k) {
      float4 av = *(const float4*)&As[k][ty * 4];
      float4 wv = *(const float4*)&Ws[k][tx * 4];
      float a4[4] = {av.x, av.y, av.z, av.w};
      float w4[4] = {wv.x, wv.y, wv.z, wv.w};
      #pragma unroll
      for (int i = 0; i < 4; ++i)
        #pragma unroll
        for (int j = 0; j < 4; ++j)
          acc[i][j] = fmaf(a4[i], w4[j], acc[i][j]);
    }
    __syncthreads();
  }
  #pragma unroll
  for (int i = 0; i < 4; ++i) {
    int m = bm + ty * 4 + i;
    #pragma unroll
    for (int j = 0; j < 4; ++j) {
      int n = bn + tx * 4 + j;
      if (n < 500) {
        float v = acc[i][j] + bias[n];
        out[m * 500 + n] = v > 0.0f ? v : 0.0f;
      }
    }
  }
}

// --------------------------- FC2: [2048,500]x[10,500]^T + b -----------------
__global__ __launch_bounds__(256) void k_fc2(
    const float* __restrict__ H, const float* __restrict__ W2,
    const float* __restrict__ b2, float* __restrict__ out) {
  int gtid = blockIdx.x * 256 + threadIdx.x;
  int b = gtid / 64, lane = gtid % 64;
  if (b >= 2048) return;
  float acc[10];
  #pragma unroll
  for (int o = 0; o < 10; ++o) acc[o] = 0.0f;
  for (int k = lane; k < 500; k += 64) {
    float a = H[b * 500 + k];
    #pragma unroll
    for (int o = 0; o < 10; ++o) acc[o] = fmaf(a, W2[o * 500 + k], acc[o]);
  }
  #pragma unroll
  for (int off = 32; off > 0; off >>= 1) {
    #pragma unroll
    for (int o = 0; o < 10; ++o) acc[o] += __shfl_down(acc[o], off);
  }
  if (lane == 0) {
    #pragma unroll
    for (int o = 0; o < 10; ++o) out[b * 10 + o] = acc[o] + b2[o];
  }
}

// ---------------------------------------------------------------------------
extern "C" void kernel_launch(void* const* d_in, const int* in_sizes, int n_in,
                              void* d_out, int out_size, void* d_ws, size_t ws_size,
                              hipStream_t stream) {
  (void)in_sizes; (void)n_in; (void)out_size; (void)ws_size;
  const float* x   = (const float*)d_in[0];
  const float* bw1 = (const float*)d_in[1];
  const float* sw1 = (const float*)d_in[2];
  const float* bw2 = (const float*)d_in[3];
  const float* sw2 = (const float*)d_in[4];
  const float* bw3 = (const float*)d_in[5];
  const float* sw3 = (const float*)d_in[6];
  const float* w1  = (const float*)d_in[7];
  const float* b1  = (const float*)d_in[8];
  const float* w2  = (const float*)d_in[9];
  const float* b2  = (const float*)d_in[10];
  float* out = (float*)d_out;

  char* ws = (char*)d_ws;
  float* W1d = (float*)(ws);               // 405 f   (1,620 B)
  float* W2d = (float*)(ws + 1664);        // 2025 f  (8,100 B)
  float* W3d = (float*)(ws + 9792);        // 810 f   (3,240 B)
  float* h1  = (float*)(ws + 16384);       // [2048,5,13,13]  6,922,240 B
  float* h2  = (float*)(ws + 16384 + 6922240);              // 4,956,160 B
  float* h3  = (float*)(ws + 16384 + 11878400);             // 1,327,104 B
  float* fc1 = (float*)(ws + 16384 + 13205504);             // 4,096,000 B

  k_prep<<<8, 256, 0, stream>>>(bw1, sw1, bw2, sw2, bw3, sw3, W1d, W2d, W3d);
  k_conv1_pool<<<2048, 256, 0, stream>>>(x, W1d, h1);
  k_kanconv<5, 13, 5, 2><<<1024, 256, 0, stream>>>(h1, W2d, h2, 2048);
  k_kanconv<5, 11, 2, 3><<<683, 256, 0, stream>>>(h2, W3d, h3, 2048);
  k_fc1<<<256, 256, 0, stream>>>(h3, w1, b1, fc1);
  k_fc2<<<512, 256, 0, stream>>>(fc1, w2, b2, out);
}